// Round 1
// 363.431 us; speedup vs baseline: 1.0185x; 1.0185x over previous
//
#include <hip/hip_runtime.h>
#include <math.h>

// Problem: N=100000 nodes, D=512, E=6400000 edges.
// gate[n] = sigmoid(dot(x[n,:], p) + b)
// out[0:2E)   = float(edge_index)            (tuple output 0, exact in f32)
// out[2E:3E)  = edge_attr[e] * gate[col[e]]  (col = edge_index[E + e])

// ---------------- Kernel 1: per-row matvec + sigmoid -----------------
// One wave (64 lanes) per TWO rows. D=512 = 64 lanes * 8 floats.
// Lane i reads float4 at [lane] and [lane+64] -> two fully-contiguous 1 KB
// segments per row per instruction (perfect coalescing). Two rows are
// processed per wave so 64 B/lane of loads are in flight and the two
// shuffle-reduction chains interleave (independent deps hide ds latency).
// p (2 KB) stays L1-resident.
__global__ __launch_bounds__(256) void gate_kernel(
    const float* __restrict__ x,
    const float* __restrict__ p,
    const float* __restrict__ b,
    float* __restrict__ gate,
    int N)
{
    const int wave_id = (blockIdx.x * blockDim.x + threadIdx.x) >> 6;
    const int lane    = threadIdx.x & 63;
    const float bb = b[0];

    const float4* pr = (const float4*)p;
    const float4 p0 = pr[lane];        // floats [4*lane .. 4*lane+3]
    const float4 p1 = pr[lane + 64];   // floats [256+4*lane ..]

    const int row0 = wave_id * 2;
    if (row0 >= N) return;
    const bool two = (row0 + 1) < N;

    const float4* xr0 = (const float4*)(x + (size_t)row0 * 512);
    const float4* xr1 = (const float4*)(x + (size_t)(two ? row0 + 1 : row0) * 512);

    // Issue all 4 row loads back-to-back (64 B/lane in flight).
    float4 a0 = xr0[lane];
    float4 a1 = xr0[lane + 64];
    float4 c0 = xr1[lane];
    float4 c1 = xr1[lane + 64];

    float s0 = a0.x * p0.x + a0.y * p0.y + a0.z * p0.z + a0.w * p0.w
             + a1.x * p1.x + a1.y * p1.y + a1.z * p1.z + a1.w * p1.w;
    float s1 = c0.x * p0.x + c0.y * p0.y + c0.z * p0.z + c0.w * p0.w
             + c1.x * p1.x + c1.y * p1.y + c1.z * p1.z + c1.w * p1.w;

    // wave64 shuffle reduction, two independent chains interleaved
    #pragma unroll
    for (int off = 32; off > 0; off >>= 1) {
        s0 += __shfl_down(s0, off, 64);
        s1 += __shfl_down(s1, off, 64);
    }
    if (lane == 0) {
        float t0 = s0 + bb;
        gate[row0] = 1.0f / (1.0f + __expf(-t0));
        if (two) {
            float t1 = s1 + bb;
            gate[row0 + 1] = 1.0f / (1.0f + __expf(-t1));
        }
    }
}

// ---------------- Kernel 2: fused index copy + edge gather/scale -----------
// Single pass over E/4 quads. Each thread reads the row-index quad, the
// col-index quad, and the attr quad ONCE, and writes all three output
// segments. This removes the 25.6 MB re-read of the col half that the
// previous two-loop version paid (conversion loop + gather loop both
// loaded edge_index[E:2E)), and keeps the whole grid active.
__global__ __launch_bounds__(256) void edge_kernel(
    const int*   __restrict__ edge_index,  // [2*E] int32
    const float* __restrict__ edge_attr,   // [E]
    const float* __restrict__ gate,        // [N] (L2-resident, 400 KB)
    float* __restrict__ out,               // [3*E] f32
    int E)
{
    const int tid    = blockIdx.x * blockDim.x + threadIdx.x;
    const int stride = gridDim.x * blockDim.x;

    const int EV4 = E >> 2;   // quads of edges

    const int4*   row4 = (const int4*)edge_index;            // [0:E)
    const int4*   col4 = (const int4*)(edge_index + E);      // [E:2E)
    const float4* ea4  = (const float4*)edge_attr;

    float4* outR = (float4*)out;                              // [0:E)
    float4* outC = (float4*)(out + (size_t)E);                // [E:2E)
    float4* outV = (float4*)(out + 2 * (size_t)E);            // [2E:3E)

    for (int i = tid; i < EV4; i += stride) {
        int4   r = row4[i];
        int4   c = col4[i];
        float4 a = ea4[i];

        outR[i] = make_float4((float)r.x, (float)r.y, (float)r.z, (float)r.w);
        outC[i] = make_float4((float)c.x, (float)c.y, (float)c.z, (float)c.w);

        float4 v;
        v.x = a.x * gate[c.x];
        v.y = a.y * gate[c.y];
        v.z = a.z * gate[c.z];
        v.w = a.w * gate[c.w];
        outV[i] = v;
    }
}

extern "C" void kernel_launch(void* const* d_in, const int* in_sizes, int n_in,
                              void* d_out, int out_size, void* d_ws, size_t ws_size,
                              hipStream_t stream) {
    const float* x          = (const float*)d_in[0];   // [N, 512]
    const int*   edge_index = (const int*)  d_in[1];   // [2, E] (int32 on device)
    const float* edge_attr  = (const float*)d_in[2];   // [E]
    const float* p          = (const float*)d_in[3];   // [512, 1]
    const float* b          = (const float*)d_in[4];   // [1]

    const int D = in_sizes[3];            // 512
    const int N = in_sizes[0] / D;        // 100000
    const int E = in_sizes[2];            // 6400000

    float* gate = (float*)d_ws;           // N floats = 400 KB scratch
    float* out  = (float*)d_out;

    // Kernel 1: one wave per 2 rows -> ceil(N/2) waves -> /4 blocks of 256
    int gate_waves  = (N + 1) / 2;
    int gate_blocks = (gate_waves + 3) / 4;        // 4 waves per 256-thread block
    gate_kernel<<<gate_blocks, 256, 0, stream>>>(x, p, b, gate, N);

    // Kernel 2: one thread per edge-quad, exact cover
    int edge_blocks = ((E / 4) + 255) / 256;       // 6250 blocks
    edge_kernel<<<edge_blocks, 256, 0, stream>>>(edge_index, edge_attr, gate, out, E);
}

// Round 3
// 351.173 us; speedup vs baseline: 1.0541x; 1.0349x over previous
//
#include <hip/hip_runtime.h>
#include <math.h>

// Problem: N=100000 nodes, D=512, E=6400000 edges.
// gate[n] = sigmoid(dot(x[n,:], p) + b)
// out[0:2E)   = float(edge_index)            (tuple output 0, exact in f32)
// out[2E:3E)  = edge_attr[e] * gate[col[e]]  (col = edge_index[E + e])

// Native clang vector types: __builtin_nontemporal_load/store requires
// pointers to scalar or NATIVE vector types (HIP_vector_type is a struct
// and is rejected).
typedef float vf4 __attribute__((ext_vector_type(4)));
typedef int   vi4 __attribute__((ext_vector_type(4)));

// ---------------- Kernel 1: per-row matvec + sigmoid -----------------
// One wave (64 lanes) per FOUR rows. D=512 = 64 lanes * 8 floats.
// Per lane: 8 nontemporal float4 loads (128 B in flight) -> 4 independent
// dot-product chains -> interleaved wave64 shuffle reductions -> lane 0
// writes a float4 of gates (row0 % 4 == 0 so the store is 16B-aligned).
// x is read-once: nontemporal keeps it from thrashing L2.
__global__ __launch_bounds__(256) void gate_kernel(
    const float* __restrict__ x,
    const float* __restrict__ p,
    const float* __restrict__ b,
    float* __restrict__ gate,
    int N)
{
    const int wave_id = (blockIdx.x * blockDim.x + threadIdx.x) >> 6;
    const int lane    = threadIdx.x & 63;
    const float bb = b[0];

    const vf4* pr = (const vf4*)p;
    const vf4 p0 = pr[lane];        // floats [4*lane .. 4*lane+3]
    const vf4 p1 = pr[lane + 64];   // floats [256+4*lane ..]

    const int row0 = wave_id * 4;
    if (row0 >= N) return;

    if (row0 + 3 < N) {
        const vf4* xr = (const vf4*)(x + (size_t)row0 * 512); // 128 vf4/row
        // Issue all 8 loads back-to-back (128 B/lane in flight).
        vf4 a0 = __builtin_nontemporal_load(xr + lane);
        vf4 a1 = __builtin_nontemporal_load(xr + lane + 64);
        vf4 b0 = __builtin_nontemporal_load(xr + lane + 128);
        vf4 b1 = __builtin_nontemporal_load(xr + lane + 192);
        vf4 c0 = __builtin_nontemporal_load(xr + lane + 256);
        vf4 c1 = __builtin_nontemporal_load(xr + lane + 320);
        vf4 d0 = __builtin_nontemporal_load(xr + lane + 384);
        vf4 d1 = __builtin_nontemporal_load(xr + lane + 448);

        float s0 = a0.x * p0.x + a0.y * p0.y + a0.z * p0.z + a0.w * p0.w
                 + a1.x * p1.x + a1.y * p1.y + a1.z * p1.z + a1.w * p1.w;
        float s1 = b0.x * p0.x + b0.y * p0.y + b0.z * p0.z + b0.w * p0.w
                 + b1.x * p1.x + b1.y * p1.y + b1.z * p1.z + b1.w * p1.w;
        float s2 = c0.x * p0.x + c0.y * p0.y + c0.z * p0.z + c0.w * p0.w
                 + c1.x * p1.x + c1.y * p1.y + c1.z * p1.z + c1.w * p1.w;
        float s3 = d0.x * p0.x + d0.y * p0.y + d0.z * p0.z + d0.w * p0.w
                 + d1.x * p1.x + d1.y * p1.y + d1.z * p1.z + d1.w * p1.w;

        // wave64 shuffle reduction, four independent chains interleaved
        #pragma unroll
        for (int off = 32; off > 0; off >>= 1) {
            s0 += __shfl_down(s0, off, 64);
            s1 += __shfl_down(s1, off, 64);
            s2 += __shfl_down(s2, off, 64);
            s3 += __shfl_down(s3, off, 64);
        }
        if (lane == 0) {
            vf4 g;
            g.x = 1.0f / (1.0f + __expf(-(s0 + bb)));
            g.y = 1.0f / (1.0f + __expf(-(s1 + bb)));
            g.z = 1.0f / (1.0f + __expf(-(s2 + bb)));
            g.w = 1.0f / (1.0f + __expf(-(s3 + bb)));
            *(vf4*)(gate + row0) = g;   // 16B-aligned (row0 % 4 == 0)
        }
    } else {
        // generic tail (not hit for N=100000, kept for safety)
        for (int row = row0; row < N; ++row) {
            const vf4* xr = (const vf4*)(x + (size_t)row * 512);
            vf4 x0 = xr[lane];
            vf4 x1 = xr[lane + 64];
            float s = x0.x * p0.x + x0.y * p0.y + x0.z * p0.z + x0.w * p0.w
                    + x1.x * p1.x + x1.y * p1.y + x1.z * p1.z + x1.w * p1.w;
            #pragma unroll
            for (int off = 32; off > 0; off >>= 1)
                s += __shfl_down(s, off, 64);
            if (lane == 0)
                gate[row] = 1.0f / (1.0f + __expf(-(s + bb)));
        }
    }
}

// ---------------- Kernel 2: fused index copy + edge gather/scale -----------
// One thread per TWO consecutive quads (32 B per stream per thread).
// All six streaming accesses (row/col/attr loads, R/C/V stores) are
// NONTEMPORAL so the 153.6 MB of streams don't evict the 400 KB gate
// array from L2 -> the random gate[col] gathers stay L2-hits.
__global__ __launch_bounds__(256) void edge_kernel(
    const int*   __restrict__ edge_index,  // [2*E] int32
    const float* __restrict__ edge_attr,   // [E]
    const float* __restrict__ gate,        // [N] (L2-resident, 400 KB)
    float* __restrict__ out,               // [3*E] f32
    int E)
{
    const int tid = blockIdx.x * blockDim.x + threadIdx.x;
    const int EV4 = E >> 2;                // quads of edges
    const int q0  = tid * 2;               // first of two quads
    if (q0 >= EV4) return;

    const vi4* row4 = (const vi4*)edge_index;            // [0:E)
    const vi4* col4 = (const vi4*)(edge_index + E);      // [E:2E)
    const vf4* ea4  = (const vf4*)edge_attr;

    vf4* outR = (vf4*)out;                                // [0:E)
    vf4* outC = (vf4*)(out + (size_t)E);                  // [E:2E)
    vf4* outV = (vf4*)(out + 2 * (size_t)E);              // [2E:3E)

    // cols first: the 8 gathers depend on them, get them in flight early
    vi4 c0 = __builtin_nontemporal_load(col4 + q0);
    vi4 c1 = __builtin_nontemporal_load(col4 + q0 + 1);
    vi4 r0 = __builtin_nontemporal_load(row4 + q0);
    vi4 r1 = __builtin_nontemporal_load(row4 + q0 + 1);
    vf4 a0 = __builtin_nontemporal_load(ea4 + q0);
    vf4 a1 = __builtin_nontemporal_load(ea4 + q0 + 1);

    // gathers (normal, cached loads: gate must stay L2-resident)
    float g0x = gate[c0.x], g0y = gate[c0.y], g0z = gate[c0.z], g0w = gate[c0.w];
    float g1x = gate[c1.x], g1y = gate[c1.y], g1z = gate[c1.z], g1w = gate[c1.w];

    vf4 fr0; fr0.x = (float)r0.x; fr0.y = (float)r0.y; fr0.z = (float)r0.z; fr0.w = (float)r0.w;
    vf4 fr1; fr1.x = (float)r1.x; fr1.y = (float)r1.y; fr1.z = (float)r1.z; fr1.w = (float)r1.w;
    vf4 fc0; fc0.x = (float)c0.x; fc0.y = (float)c0.y; fc0.z = (float)c0.z; fc0.w = (float)c0.w;
    vf4 fc1; fc1.x = (float)c1.x; fc1.y = (float)c1.y; fc1.z = (float)c1.z; fc1.w = (float)c1.w;

    __builtin_nontemporal_store(fr0, outR + q0);
    __builtin_nontemporal_store(fr1, outR + q0 + 1);
    __builtin_nontemporal_store(fc0, outC + q0);
    __builtin_nontemporal_store(fc1, outC + q0 + 1);

    vf4 v0, v1;
    v0.x = a0.x * g0x;  v0.y = a0.y * g0y;  v0.z = a0.z * g0z;  v0.w = a0.w * g0w;
    v1.x = a1.x * g1x;  v1.y = a1.y * g1y;  v1.z = a1.z * g1z;  v1.w = a1.w * g1w;
    __builtin_nontemporal_store(v0, outV + q0);
    __builtin_nontemporal_store(v1, outV + q0 + 1);
}

extern "C" void kernel_launch(void* const* d_in, const int* in_sizes, int n_in,
                              void* d_out, int out_size, void* d_ws, size_t ws_size,
                              hipStream_t stream) {
    const float* x          = (const float*)d_in[0];   // [N, 512]
    const int*   edge_index = (const int*)  d_in[1];   // [2, E] (int32 on device)
    const float* edge_attr  = (const float*)d_in[2];   // [E]
    const float* p          = (const float*)d_in[3];   // [512, 1]
    const float* b          = (const float*)d_in[4];   // [1]

    const int D = in_sizes[3];            // 512
    const int N = in_sizes[0] / D;        // 100000
    const int E = in_sizes[2];            // 6400000

    float* gate = (float*)d_ws;           // N floats = 400 KB scratch
    float* out  = (float*)d_out;

    // Kernel 1: one wave per 4 rows -> 25000 waves -> 6250 blocks of 256
    int gate_waves  = (N + 3) / 4;
    int gate_blocks = (gate_waves + 3) / 4;
    gate_kernel<<<gate_blocks, 256, 0, stream>>>(x, p, b, gate, N);

    // Kernel 2: one thread per 2 edge-quads -> E/8 = 800000 threads -> 3125 blocks
    int edge_threads = (E >> 2) / 2;
    int edge_blocks  = (edge_threads + 255) / 256;
    edge_kernel<<<edge_blocks, 256, 0, stream>>>(edge_index, edge_attr, gate, out, E);
}